// Round 9
// baseline (653.711 us; speedup 1.0000x reference)
//
#include <hip/hip_runtime.h>

#define N_NODES 40000
#define N_EDGES 640000
#define EMB 128
#define NF ((size_t)N_NODES * EMB)
#define RCP_N (1.0f / (float)N_NODES)
#define BN_EPS 1e-5f
#define CAP 64          // fixed bucket capacity (avg deg 16; P(>64) ~ 1e-18)

typedef _Float16 f16x8v __attribute__((ext_vector_type(8)));
typedef float f32x4v __attribute__((ext_vector_type(4)));
typedef unsigned short ushort8v __attribute__((ext_vector_type(8)));

__device__ __forceinline__ unsigned short f2h(float v) {
    return __builtin_bit_cast(unsigned short, (_Float16)v);
}
__device__ __forceinline__ float h2f(unsigned short u) {
    return (float)__builtin_bit_cast(_Float16, u);
}

// ---------------------------------------------------------------------------
// GEMM body (direct-global operands, f16 in/out, f32 accum).
// wave = 16 rows x 128 cols; 4 waves = 64-row tile at row0.
// ---------------------------------------------------------------------------
template<int AMODE, bool RSC>
__device__ __forceinline__ void gemm_body(
    int row0, int t,
    const unsigned short* __restrict__ A, const unsigned short* __restrict__ A2,
    const unsigned short* __restrict__ Wt,
    const float* __restrict__ bias, const float* __restrict__ rowscale,
    const float* C1, const float* D1, const float* C2, const float* D2,
    const float* AE, const float* BE, const float* CE,
    const float* __restrict__ sN, const float* __restrict__ cN,
    unsigned short* __restrict__ Out, float* __restrict__ stats_out,
    float (*redS)[128], float (*redQ)[128])
{
    const int w = t >> 6, lane = t & 63;
    const int la = lane & 15, lb = lane >> 4;
    const int ar = row0 + (w << 4) + la;
    const int kb = lb * 8;

    f16x8v afrag[4];
    #pragma unroll
    for (int s = 0; s < 4; ++s) {
        ushort8v av = *(const ushort8v*)&A[(size_t)ar * 128 + s * 32 + kb];
        if (AMODE == 0) {
            afrag[s] = __builtin_bit_cast(f16x8v, av);
        } else if (AMODE == 1) {
            f16x8v o;
            #pragma unroll
            for (int j = 0; j < 8; ++j) {
                int q = s * 32 + kb + j;
                o[j] = (_Float16)fmaxf(0.f, fmaf(h2f(av[j]), C1[q], D1[q]));
            }
            afrag[s] = o;
        } else {
            ushort8v gv = *(const ushort8v*)&A2[(size_t)ar * 128 + s * 32 + kb];
            float sr = sN[ar], cr = cN[ar];
            f16x8v o;
            #pragma unroll
            for (int j = 0; j < 8; ++j) {
                int q = s * 32 + kb + j;
                float y = h2f(av[j]) * C1[q] + D1[q] + h2f(gv[j]) * C2[q] + D2[q]
                        + sr * AE[q] + cr * BE[q] + CE[q];
                o[j] = (_Float16)fmaxf(0.f, y);
            }
            afrag[s] = o;
        }
    }
    // in-place safety: all A/A2 reads of this 64-row block complete before
    // any epilogue write (vmcnt drained before s_barrier)
    __syncthreads();

    f32x4v acc[8];
    #pragma unroll
    for (int c = 0; c < 8; ++c) acc[c] = (f32x4v){0.f, 0.f, 0.f, 0.f};

    #pragma unroll
    for (int c = 0; c < 8; ++c) {
        int bn_ = (c << 4) + la;
        #pragma unroll
        for (int s = 0; s < 4; ++s) {
            ushort8v bw = *(const ushort8v*)&Wt[(size_t)bn_ * 128 + s * 32 + kb];
            acc[c] = __builtin_amdgcn_mfma_f32_16x16x32_f16(
                afrag[s], __builtin_bit_cast(f16x8v, bw), acc[c], 0, 0, 0);
        }
    }

    const int orow0 = row0 + (w << 4) + lb * 4;
    float rsj[4];
    if (RSC) {
        #pragma unroll
        for (int j = 0; j < 4; ++j) rsj[j] = rowscale[orow0 + j];
    }
    float csum[8], csq[8];
    #pragma unroll
    for (int c = 0; c < 8; ++c) {
        int col = (c << 4) + la;
        float bc = bias[col];
        float s0 = 0.f, s1 = 0.f;
        #pragma unroll
        for (int j = 0; j < 4; ++j) {
            float v = acc[c][j] + (RSC ? rsj[j] * bc : bc);
            Out[(size_t)(orow0 + j) * 128 + col] = f2h(v);
            s0 += v; s1 += v * v;
        }
        csum[c] = s0; csq[c] = s1;
    }
    #pragma unroll
    for (int c = 0; c < 8; ++c) {
        csum[c] += __shfl_xor(csum[c], 16);
        csum[c] += __shfl_xor(csum[c], 32);
        csq[c]  += __shfl_xor(csq[c], 16);
        csq[c]  += __shfl_xor(csq[c], 32);
    }
    if (lane < 16) {
        #pragma unroll
        for (int c = 0; c < 8; ++c) {
            redS[w][(c << 4) + lane] = csum[c];
            redQ[w][(c << 4) + lane] = csq[c];
        }
    }
    __syncthreads();
    if (t < 128) {
        atomicAdd(&stats_out[t], redS[0][t] + redS[1][t] + redS[2][t] + redS[3][t]);
        atomicAdd(&stats_out[128 + t], redQ[0][t] + redQ[1][t] + redQ[2][t] + redQ[3][t]);
    }
}

// ---------------------------------------------------------------------------
// Prep mega-kernel: blocks [0,48) wprep | [48,673) init_node | [673,3173) edge
// All three roles independent.
// ---------------------------------------------------------------------------
__global__ __launch_bounds__(256) void prep_kernel(
    const float* __restrict__ Wnode, const float* __restrict__ Wnb,
    const float* __restrict__ Wm1, const float* __restrict__ Wm2,
    unsigned short* __restrict__ Wt,
    const float* __restrict__ na, const float* __restrict__ W0,
    const float* __restrict__ b0, unsigned short* __restrict__ Z,
    float* __restrict__ st,
    const int* __restrict__ ei, const float* __restrict__ ea,
    unsigned long long* __restrict__ scP, unsigned* __restrict__ cursor,
    int* __restrict__ slot)
{
    __shared__ float tile[32][129];      // wprep
    __shared__ float red[256];           // init
    const int blk = blockIdx.x;
    const int t = threadIdx.x;

    if (blk < 48) {
        // ---- weight transpose+f16: mat = blk>>2, k-chunk = (blk&3)*32
        int mat = blk >> 2, kc = (blk & 3) * 32;
        int grp = mat / 3, lay = mat % 3;
        const float* src = (grp == 0) ? Wnode : (grp == 1) ? Wnb
                         : (grp == 2) ? Wm1 : Wm2;
        src += (size_t)lay * 16384;
        #pragma unroll
        for (int i = 0; i < 16; ++i) {
            int idx = t + i * 256;
            int r = idx >> 7, n = idx & 127;
            tile[r][n] = src[(size_t)(kc + r) * 128 + n];
        }
        __syncthreads();
        int n = t >> 1, h = (t & 1) * 16;
        ushort8v o0, o1;
        #pragma unroll
        for (int j = 0; j < 8; ++j) o0[j] = f2h(tile[h + j][n]);
        #pragma unroll
        for (int j = 0; j < 8; ++j) o1[j] = f2h(tile[h + 8 + j][n]);
        unsigned short* dst = &Wt[(size_t)mat * 16384 + n * 128 + kc + h];
        *(ushort8v*)dst = o0;
        *(ushort8v*)(dst + 8) = o1;
    } else if (blk < 673) {
        // ---- initial node MLP (K=2) + column stats
        int col = t & 127, rh = t >> 7;
        float w0 = W0[col], w1 = W0[128 + col], bb = b0[col];
        int rbase = (blk - 48) * 64;
        float sm = 0.f, sq = 0.f;
        #pragma unroll 4
        for (int i = 0; i < 32; ++i) {
            int r = rbase + rh + i * 2;
            float2 nv = *(const float2*)&na[r * 2];
            float v = fmaf(nv.x, w0, fmaf(nv.y, w1, bb));
            Z[(size_t)r * 128 + col] = f2h(v);
            sm += v; sq += v * v;
        }
        red[t] = sm; __syncthreads();
        if (t < 128) atomicAdd(&st[t], red[t] + red[t + 128]);
        __syncthreads();
        red[t] = sq; __syncthreads();
        if (t < 128) atomicAdd(&st[128 + t], red[t] + red[t + 128]);
    } else {
        // ---- per-edge pass: 1 edge/thread (max outstanding atomics)
        int e = (blk - 673) * 256 + t;     // 2500*256 == N_EDGES
        int r = ei[e];
        int d = ei[N_EDGES + e];
        int fx = (int)rintf(ea[e] * 65536.0f);
        unsigned long long add =
            (((unsigned long long)(unsigned)(fx + 0x40000000)) << 20) | 1ULL;
        atomicAdd(&scP[r], add);
        unsigned pos = atomicAdd(&cursor[d], 1u);
        slot[(size_t)d * CAP + (pos < CAP ? pos : CAP - 1)] = r;
    }
}

// Decode scP -> sN, cN + scalar moments; cursor -> f32 deg.  grid 157
__global__ __launch_bounds__(256) void decode_kernel(
    const unsigned long long* __restrict__ scP, const unsigned* __restrict__ cursor,
    float* __restrict__ sN, float* __restrict__ cN, float* __restrict__ dgf,
    float* __restrict__ mom)
{
    int t = threadIdx.x;
    int i = blockIdx.x * 256 + t;
    float a0 = 0.f, a1 = 0.f, a2 = 0.f, a3 = 0.f, a4 = 0.f;
    if (i < N_NODES) {
        unsigned long long v = scP[i];
        unsigned cnt = (unsigned)(v & 0xFFFFFULL);
        long long sp = (long long)(v >> 20) - ((long long)cnt << 30);
        float s = (float)sp * (1.0f / 65536.0f);
        float c = (float)cnt;
        sN[i] = s; cN[i] = c;
        dgf[i] = (float)cursor[i];
        a0 = s; a1 = s * s; a2 = c; a3 = c * c; a4 = s * c;
    }
    #pragma unroll
    for (int off = 32; off > 0; off >>= 1) {
        a0 += __shfl_down(a0, off);
        a1 += __shfl_down(a1, off);
        a2 += __shfl_down(a2, off);
        a3 += __shfl_down(a3, off);
        a4 += __shfl_down(a4, off);
    }
    if ((t & 63) == 0) {
        atomicAdd(&mom[0], a0);
        atomicAdd(&mom[1], a1);
        atomicAdd(&mom[2], a2);
        atomicAdd(&mom[3], a3);
        atomicAdd(&mom[4], a4);
    }
}

// ---------------------------------------------------------------------------
// Merged gather + node-branch GEMM (both need the same bn transform C1/D1):
//   blocks [0,10000): G[d] = sum relu(bn(P[slot[d][j]]))  (1 wave/node)
//   blocks [10000,10625): ZN = relu(bn(P)) @ Wnode + bnode (+stats)
// ---------------------------------------------------------------------------
__global__ __launch_bounds__(256) void gather_zn_kernel(
    const unsigned* __restrict__ cnt, const int* __restrict__ slot,
    const unsigned short* __restrict__ Ph,
    const float* __restrict__ st1, const float* __restrict__ g1,
    const float* __restrict__ bt1,
    const unsigned short* __restrict__ Wt, const float* __restrict__ bias,
    unsigned short* __restrict__ Gh, unsigned short* __restrict__ ZNh,
    float* __restrict__ stats_out)
{
    __shared__ float C1[128], D1[128];
    __shared__ float redS[4][128], redQ[4][128];
    const int t = threadIdx.x;
    if (t < 128) {
        float m = st1[t] * RCP_N;
        float v = st1[128 + t] * RCP_N - m * m;
        float a = g1[t] * rsqrtf(v + BN_EPS);
        C1[t] = a; D1[t] = bt1[t] - m * a;
    }
    __syncthreads();

    if (blockIdx.x < 10000) {
        int wid = (blockIdx.x * 256 + t) >> 6;
        int lane = t & 63;
        int half = lane >> 5, l32 = lane & 31;
        float4 a4 = *(const float4*)&C1[l32 * 4];
        float4 b4 = *(const float4*)&D1[l32 * 4];
        int n = (int)cnt[wid];
        n = n < CAP ? n : CAP;
        const int* sl = &slot[(size_t)wid * CAP];
        f32x4v s0 = {0.f, 0.f, 0.f, 0.f}, s1 = {0.f, 0.f, 0.f, 0.f};
        int j = half;
        for (; j + 2 < n; j += 4) {
            int r0 = sl[j], r1 = sl[j + 2];
            ushort4 v0 = *(const ushort4*)&Ph[(size_t)r0 * 128 + l32 * 4];
            ushort4 v1 = *(const ushort4*)&Ph[(size_t)r1 * 128 + l32 * 4];
            s0[0] += fmaxf(0.f, fmaf(h2f(v0.x), a4.x, b4.x));
            s0[1] += fmaxf(0.f, fmaf(h2f(v0.y), a4.y, b4.y));
            s0[2] += fmaxf(0.f, fmaf(h2f(v0.z), a4.z, b4.z));
            s0[3] += fmaxf(0.f, fmaf(h2f(v0.w), a4.w, b4.w));
            s1[0] += fmaxf(0.f, fmaf(h2f(v1.x), a4.x, b4.x));
            s1[1] += fmaxf(0.f, fmaf(h2f(v1.y), a4.y, b4.y));
            s1[2] += fmaxf(0.f, fmaf(h2f(v1.z), a4.z, b4.z));
            s1[3] += fmaxf(0.f, fmaf(h2f(v1.w), a4.w, b4.w));
        }
        for (; j < n; j += 2) {
            int r0 = sl[j];
            ushort4 v0 = *(const ushort4*)&Ph[(size_t)r0 * 128 + l32 * 4];
            s0[0] += fmaxf(0.f, fmaf(h2f(v0.x), a4.x, b4.x));
            s0[1] += fmaxf(0.f, fmaf(h2f(v0.y), a4.y, b4.y));
            s0[2] += fmaxf(0.f, fmaf(h2f(v0.z), a4.z, b4.z));
            s0[3] += fmaxf(0.f, fmaf(h2f(v0.w), a4.w, b4.w));
        }
        #pragma unroll
        for (int q = 0; q < 4; ++q) {
            float v = s0[q] + s1[q];
            v += __shfl_xor(v, 32);
            s0[q] = v;
        }
        if (half == 0) {
            ushort4 o;
            o.x = f2h(s0[0]); o.y = f2h(s0[1]);
            o.z = f2h(s0[2]); o.w = f2h(s0[3]);
            *(ushort4*)&Gh[(size_t)wid * 128 + l32 * 4] = o;
        }
    } else {
        gemm_body<1, false>((blockIdx.x - 10000) * 64, t,
            Ph, nullptr, Wt, bias, nullptr,
            C1, D1, nullptr, nullptr, nullptr, nullptr, nullptr,
            nullptr, nullptr, ZNh, stats_out, redS, redQ);
    }
}

// ---------------------------------------------------------------------------
// Standalone GEMM kernels (direct-global operands). grid 625.
// ---------------------------------------------------------------------------
template<int AMODE, bool RSC>
__global__ __launch_bounds__(256) void mfma_gemm_kernel(
    const unsigned short* __restrict__ A, const unsigned short* __restrict__ A2,
    const unsigned short* __restrict__ Wt,
    const float* __restrict__ bias, const float* __restrict__ rowscale,
    const float* __restrict__ st1, const float* __restrict__ g1, const float* __restrict__ bt1,
    const float* __restrict__ st2, const float* __restrict__ g2, const float* __restrict__ bt2,
    const float* __restrict__ sN, const float* __restrict__ cN,
    const float* __restrict__ scal,
    const float* __restrict__ We, const float* __restrict__ Be,
    const float* __restrict__ ge, const float* __restrict__ bte,
    unsigned short* __restrict__ Out, float* __restrict__ stats_out)
{
    __shared__ float C1[128], D1[128], C2[128], D2[128];
    __shared__ float AE[128], BE[128], CE[128];
    __shared__ float redS[4][128], redQ[4][128];
    const int t = threadIdx.x;

    if (AMODE == 1) {
        if (t < 128) {
            float m = st1[t] * RCP_N;
            float v = st1[128 + t] * RCP_N - m * m;
            float a = g1[t] * rsqrtf(v + BN_EPS);
            C1[t] = a; D1[t] = bt1[t] - m * a;
        }
        __syncthreads();
    } else if (AMODE == 2) {
        if (t < 128) {
            float m = st1[t] * RCP_N;
            float v = st1[128 + t] * RCP_N - m * m;
            float a = g1[t] * rsqrtf(v + BN_EPS);
            C1[t] = a; D1[t] = bt1[t] - m * a;

            m = st2[t] * RCP_N;
            v = st2[128 + t] * RCP_N - m * m;
            float a2c = g2[t] * rsqrtf(v + BN_EPS);
            C2[t] = a2c; D2[t] = bt2[t] - m * a2c;

            float ms = scal[0] * RCP_N, vs = scal[1] * RCP_N - ms * ms;
            float mc = scal[2] * RCP_N, vc = scal[3] * RCP_N - mc * mc;
            float cov = scal[4] * RCP_N - ms * mc;
            float we = We[t], be = Be[t];
            float me = ms * we + mc * be;
            float ve = we * we * vs + be * be * vc + 2.f * we * be * cov;
            float ae = ge[t] * rsqrtf(ve + BN_EPS);
            AE[t] = we * ae; BE[t] = be * ae; CE[t] = bte[t] - me * ae;
        }
        __syncthreads();
    }

    gemm_body<AMODE, RSC>(blockIdx.x * 64, t,
        A, A2, Wt, bias, rowscale,
        C1, D1, C2, D2, AE, BE, CE,
        sN, cN, Out, stats_out, redS, redQ);
}

// Final elementwise: out(f32) = relu(bn(Z f16))
__global__ __launch_bounds__(256) void bnrelu_kernel(
    const unsigned short* __restrict__ Z, const float* __restrict__ stz,
    const float* __restrict__ g, const float* __restrict__ bt,
    float* __restrict__ O)
{
    __shared__ float aT[128], bT[128];
    int t = threadIdx.x;
    if (t < 128) {
        float m = stz[t] * RCP_N;
        float v = stz[128 + t] * RCP_N - m * m;
        float a = g[t] * rsqrtf(v + BN_EPS);
        aT[t] = a; bT[t] = bt[t] - m * a;
    }
    __syncthreads();
    int stride = gridDim.x * 256;
    for (int idx = blockIdx.x * 256 + t; idx < N_NODES * 32; idx += stride) {
        int r = idx >> 5;
        int q = (idx & 31) * 4;
        ushort4 z = *(const ushort4*)&Z[(size_t)r * 128 + q];
        float4 o;
        o.x = fmaxf(0.f, fmaf(h2f(z.x), aT[q],     bT[q]));
        o.y = fmaxf(0.f, fmaf(h2f(z.y), aT[q + 1], bT[q + 1]));
        o.z = fmaxf(0.f, fmaf(h2f(z.z), aT[q + 2], bT[q + 2]));
        o.w = fmaxf(0.f, fmaf(h2f(z.w), aT[q + 3], bT[q + 3]));
        *(float4*)&O[(size_t)r * 128 + q] = o;
    }
}

// ---------------------------------------------------------------------------
extern "C" void kernel_launch(void* const* d_in, const int* in_sizes, int n_in,
                              void* d_out, int out_size, void* d_ws, size_t ws_size,
                              hipStream_t stream)
{
    const float* node_attr = (const float*)d_in[0];
    const int*   ei        = (const int*)d_in[1];
    const float* ea        = (const float*)d_in[2];
    const float* W0    = (const float*)d_in[3];
    const float* b0    = (const float*)d_in[4];
    const float* g0    = (const float*)d_in[5];
    const float* bt0   = (const float*)d_in[6];
    const float* Wnode = (const float*)d_in[7];
    const float* bnode = (const float*)d_in[8];
    const float* Wedge = (const float*)d_in[9];
    const float* bedge = (const float*)d_in[10];
    const float* Wnb   = (const float*)d_in[11];
    const float* bnb   = (const float*)d_in[12];
    const float* gn    = (const float*)d_in[13];
    const float* ge    = (const float*)d_in[14];
    const float* gnb   = (const float*)d_in[15];
    const float* gm1   = (const float*)d_in[16];
    const float* gm2   = (const float*)d_in[17];
    const float* btn   = (const float*)d_in[18];
    const float* bte   = (const float*)d_in[19];
    const float* btnb  = (const float*)d_in[20];
    const float* btm1  = (const float*)d_in[21];
    const float* btm2  = (const float*)d_in[22];
    const float* Wm1   = (const float*)d_in[23];
    const float* bm1   = (const float*)d_in[24];
    const float* Wm2   = (const float*)d_in[25];
    const float* bm2   = (const float*)d_in[26];
    float* out = (float*)d_out;

    // workspace: Ph|ZNh|Gh (f16, NF each) | sN|cN|dg (f32) | st(4096)
    //            | scP(u64,N) | cursor(u32,N) | slot(int, N*CAP) | Wtb(f16)
    unsigned short* Ph  = (unsigned short*)d_ws;
    unsigned short* ZNh = Ph + NF;
    unsigned short* Gh  = ZNh + NF;
    float* sN = (float*)(Gh + NF);
    float* cN = sN + N_NODES;
    float* dg = cN + N_NODES;
    float* st = dg + N_NODES;
    unsigned long long* scP = (unsigned long long*)(st + 4096);
    unsigned* cursor = (unsigned*)(scP + N_NODES);
    int* slot = (int*)(cursor + N_NODES);
    unsigned short* Wtb = (unsigned short*)(slot + (size_t)N_NODES * CAP);
    // stats: st[0..255] init | st[256..260] moments | layer i at 264+i*1024:
    //   zn(+0), aggr(+256), z1(+512), z2(+768)

    // zero st | scP | cursor (contiguous: 4096 + 3N floats)
    (void)hipMemsetAsync(st, 0, (size_t)(4096 + 3 * N_NODES) * sizeof(float), stream);
    prep_kernel<<<3173, 256, 0, stream>>>(
        Wnode, Wnb, Wm1, Wm2, Wtb,
        node_attr, W0, b0, Ph, st,
        ei, ea, scP, cursor, slot);
    decode_kernel<<<157, 256, 0, stream>>>(scP, cursor, sN, cN, dg, st + 256);

    const float* xst = st;
    const float* xg  = g0;
    const float* xbt = bt0;

    for (int i = 0; i < 3; ++i) {
        float* lay = st + 264 + i * 1024;
        // gather (G) + node-branch GEMM (ZN), fused dispatch
        gather_zn_kernel<<<10625, 256, 0, stream>>>(
            cursor, slot, Ph, xst, xg, xbt,
            Wtb + (size_t)(0 + i) * 16384, bnode + i * 128,
            Gh, ZNh, lay);
        // neighbor branch: G = G @ Wnb + deg*bnb (+stats), in place
        mfma_gemm_kernel<0, true><<<625, 256, 0, stream>>>(
            Gh, nullptr, Wtb + (size_t)(3 + i) * 16384, bnb + i * 128, dg,
            nullptr, nullptr, nullptr, nullptr, nullptr, nullptr,
            nullptr, nullptr, nullptr, nullptr, nullptr, nullptr, nullptr,
            Gh, lay + 256);
        // z1 = relu(bn(ZN)+bn(G)+ea) @ Wm1 + bm1 (+stats) -> ZN (fused combine)
        mfma_gemm_kernel<2, false><<<625, 256, 0, stream>>>(
            ZNh, Gh, Wtb + (size_t)(6 + i) * 16384, bm1 + i * 128, nullptr,
            lay, gn + i * 128, btn + i * 128,
            lay + 256, gnb + i * 128, btnb + i * 128,
            sN, cN, st + 256,
            Wedge + i * 128, bedge + i * 128, ge + i * 128, bte + i * 128,
            ZNh, lay + 512);
        // z2 = relu(bn(z1)) @ Wm2 + bm2 (+stats) -> P
        mfma_gemm_kernel<1, false><<<625, 256, 0, stream>>>(
            ZNh, nullptr, Wtb + (size_t)(9 + i) * 16384, bm2 + i * 128, nullptr,
            lay + 512, gm1 + i * 128, btm1 + i * 128, nullptr, nullptr, nullptr,
            nullptr, nullptr, nullptr, nullptr, nullptr, nullptr, nullptr,
            Ph, lay + 768);

        xst = lay + 768;
        xg  = gm2 + i * 128;
        xbt = btm2 + i * 128;
    }
    bnrelu_kernel<<<2048, 256, 0, stream>>>(Ph, xst, xg, xbt, out);
}

// Round 10
// 428.931 us; speedup vs baseline: 1.5240x; 1.5240x over previous
//
#include <hip/hip_runtime.h>

#define N_NODES 40000
#define N_EDGES 640000
#define EMB 128
#define NF ((size_t)N_NODES * EMB)
#define RCP_N (1.0f / (float)N_NODES)
#define BN_EPS 1e-5f
#define CAP 64          // fixed bucket capacity (avg deg 16; P(>64) ~ 1e-18)
#define NSLICE 16       // stats accumulator slices (atomic contention fix)
#define STB (NSLICE * 256)   // floats per sliced stat block

typedef _Float16 f16x8v __attribute__((ext_vector_type(8)));
typedef float f32x4v __attribute__((ext_vector_type(4)));
typedef unsigned short ushort8v __attribute__((ext_vector_type(8)));

__device__ __forceinline__ unsigned short f2h(float v) {
    return __builtin_bit_cast(unsigned short, (_Float16)v);
}
__device__ __forceinline__ float h2f(unsigned short u) {
    return (float)__builtin_bit_cast(_Float16, u);
}

// Sum NSLICE slices of a stat block -> bn scale/shift (threads t<128)
__device__ __forceinline__ void bn_prep(
    const float* __restrict__ stat, const float* __restrict__ g,
    const float* __restrict__ bt, float* C, float* D, int t)
{
    if (t < 128) {
        float sm = 0.f, sq = 0.f;
        #pragma unroll
        for (int s = 0; s < NSLICE; ++s) {
            sm += stat[s * 256 + t];
            sq += stat[s * 256 + 128 + t];
        }
        float m = sm * RCP_N;
        float v = sq * RCP_N - m * m;
        float a = g[t] * rsqrtf(v + BN_EPS);
        C[t] = a; D[t] = bt[t] - m * a;
    }
}

// ---------------------------------------------------------------------------
// Per-edge pass (1 edge/thread = max outstanding atomics):
//  - scP[row] += pack(ea,1);  pos = cursor[col]++; slot[col*CAP+pos] = row
// ---------------------------------------------------------------------------
__global__ __launch_bounds__(256) void edge_slot_kernel(
    const int* __restrict__ ei, const float* __restrict__ ea,
    unsigned long long* __restrict__ scP, unsigned* __restrict__ cursor,
    int* __restrict__ slot)
{
    int e = blockIdx.x * 256 + threadIdx.x;   // grid = 2500*256 == N_EDGES
    int r = ei[e];
    int d = ei[N_EDGES + e];
    int fx = (int)rintf(ea[e] * 65536.0f);
    unsigned long long add =
        (((unsigned long long)(unsigned)(fx + 0x40000000)) << 20) | 1ULL;
    atomicAdd(&scP[r], add);
    unsigned pos = atomicAdd(&cursor[d], 1u);
    slot[(size_t)d * CAP + (pos < CAP ? pos : CAP - 1)] = r;
}

// Decode scP -> sN, cN + scalar moments; cursor -> f32 deg.  grid 157
__global__ __launch_bounds__(256) void decode_kernel(
    const unsigned long long* __restrict__ scP, const unsigned* __restrict__ cursor,
    float* __restrict__ sN, float* __restrict__ cN, float* __restrict__ dgf,
    float* __restrict__ mom)
{
    int t = threadIdx.x;
    int i = blockIdx.x * 256 + t;
    float a0 = 0.f, a1 = 0.f, a2 = 0.f, a3 = 0.f, a4 = 0.f;
    if (i < N_NODES) {
        unsigned long long v = scP[i];
        unsigned cnt = (unsigned)(v & 0xFFFFFULL);
        long long sp = (long long)(v >> 20) - ((long long)cnt << 30);
        float s = (float)sp * (1.0f / 65536.0f);
        float c = (float)cnt;
        sN[i] = s; cN[i] = c;
        dgf[i] = (float)cursor[i];
        a0 = s; a1 = s * s; a2 = c; a3 = c * c; a4 = s * c;
    }
    #pragma unroll
    for (int off = 32; off > 0; off >>= 1) {
        a0 += __shfl_down(a0, off);
        a1 += __shfl_down(a1, off);
        a2 += __shfl_down(a2, off);
        a3 += __shfl_down(a3, off);
        a4 += __shfl_down(a4, off);
    }
    if ((t & 63) == 0) {
        atomicAdd(&mom[0], a0);
        atomicAdd(&mom[1], a1);
        atomicAdd(&mom[2], a2);
        atomicAdd(&mom[3], a3);
        atomicAdd(&mom[4], a4);
    }
}

// ---------------------------------------------------------------------------
// Initial node MLP: P(f16) = node_attr @ W0 + b0 (K=2), sliced col stats
// ---------------------------------------------------------------------------
__global__ __launch_bounds__(256) void init_node_kernel(
    const float* __restrict__ na, const float* __restrict__ W0,
    const float* __restrict__ b0, unsigned short* __restrict__ Z,
    float* __restrict__ st)
{
    int t = threadIdx.x;
    int col = t & 127, rh = t >> 7;
    float w0 = W0[col], w1 = W0[128 + col], bb = b0[col];
    int rbase = blockIdx.x * 64;
    float sm = 0.f, sq = 0.f;
    #pragma unroll 4
    for (int i = 0; i < 32; ++i) {
        int r = rbase + rh + i * 2;
        float2 nv = *(const float2*)&na[r * 2];
        float v = fmaf(nv.x, w0, fmaf(nv.y, w1, bb));
        Z[(size_t)r * 128 + col] = f2h(v);
        sm += v; sq += v * v;
    }
    __shared__ float red[256];
    float* stS = st + (blockIdx.x & (NSLICE - 1)) * 256;
    red[t] = sm; __syncthreads();
    if (t < 128) atomicAdd(&stS[t], red[t] + red[t + 128]);
    __syncthreads();
    red[t] = sq; __syncthreads();
    if (t < 128) atomicAdd(&stS[128 + t], red[t] + red[t + 128]);
}

// ---------------------------------------------------------------------------
// Weight prep: Wt[mat][n][k] = f16(W[mat][k][n]), 12 matrices of 128x128.
// ---------------------------------------------------------------------------
__global__ __launch_bounds__(256) void wprep_kernel(
    const float* __restrict__ Wnode, const float* __restrict__ Wnb,
    const float* __restrict__ Wm1, const float* __restrict__ Wm2,
    unsigned short* __restrict__ Wt)
{
    __shared__ float tile[32][129];
    int b = blockIdx.x;
    int mat = b >> 2, kc = (b & 3) * 32;
    int grp = mat / 3, lay = mat % 3;
    const float* src = (grp == 0) ? Wnode : (grp == 1) ? Wnb : (grp == 2) ? Wm1 : Wm2;
    src += (size_t)lay * 16384;
    int t = threadIdx.x;
    #pragma unroll
    for (int i = 0; i < 16; ++i) {
        int idx = t + i * 256;
        int r = idx >> 7, n = idx & 127;
        tile[r][n] = src[(size_t)(kc + r) * 128 + n];
    }
    __syncthreads();
    int n = t >> 1, h = (t & 1) * 16;
    ushort8v o0, o1;
    #pragma unroll
    for (int j = 0; j < 8; ++j) o0[j] = f2h(tile[h + j][n]);
    #pragma unroll
    for (int j = 0; j < 8; ++j) o1[j] = f2h(tile[h + 8 + j][n]);
    unsigned short* dst = &Wt[(size_t)mat * 16384 + n * 128 + kc + h];
    *(ushort8v*)dst = o0;
    *(ushort8v*)(dst + 8) = o1;
}

// ---------------------------------------------------------------------------
// Gather with inline bn+relu: G[d] = sum relu(a*P[slot[d][j]]+b)
// Quarter-wave (16 lanes x 16B = one 256B row) per row; 4 rows across
// quarters x 2-deep unroll = 8 loads in flight per wave.
// ---------------------------------------------------------------------------
__global__ __launch_bounds__(256) void gather_bn_kernel(
    const unsigned* __restrict__ cnt, const int* __restrict__ slot,
    const unsigned short* __restrict__ Ph,
    const float* __restrict__ stat, const float* __restrict__ g_in,
    const float* __restrict__ bt_in,
    unsigned short* __restrict__ Gh)
{
    __shared__ float aT[128], bT[128];
    int t = threadIdx.x;
    bn_prep(stat, g_in, bt_in, aT, bT, t);
    __syncthreads();
    int wid = (blockIdx.x * 256 + t) >> 6;   // grid 10000 -> 40000 waves
    int lane = t & 63;
    int q = lane >> 4, l16 = lane & 15;
    int cb = l16 * 8;
    float av[8], bv[8];
    #pragma unroll
    for (int k = 0; k < 8; ++k) { av[k] = aT[cb + k]; bv[k] = bT[cb + k]; }
    int n = (int)cnt[wid];
    n = n < CAP ? n : CAP;
    const int* sl = &slot[(size_t)wid * CAP];
    float s0[8] = {0}, s1[8] = {0};
    int j = q;
    for (; j + 4 < n; j += 8) {
        int r0 = sl[j], r1 = sl[j + 4];
        ushort8v v0 = *(const ushort8v*)&Ph[(size_t)r0 * 128 + cb];
        ushort8v v1 = *(const ushort8v*)&Ph[(size_t)r1 * 128 + cb];
        #pragma unroll
        for (int k = 0; k < 8; ++k) {
            s0[k] += fmaxf(0.f, fmaf(h2f(v0[k]), av[k], bv[k]));
            s1[k] += fmaxf(0.f, fmaf(h2f(v1[k]), av[k], bv[k]));
        }
    }
    for (; j < n; j += 4) {
        int r0 = sl[j];
        ushort8v v0 = *(const ushort8v*)&Ph[(size_t)r0 * 128 + cb];
        #pragma unroll
        for (int k = 0; k < 8; ++k)
            s0[k] += fmaxf(0.f, fmaf(h2f(v0[k]), av[k], bv[k]));
    }
    #pragma unroll
    for (int k = 0; k < 8; ++k) {
        float v = s0[k] + s1[k];
        v += __shfl_xor(v, 16);
        v += __shfl_xor(v, 32);
        s0[k] = v;
    }
    if (q == 0) {
        ushort8v o;
        #pragma unroll
        for (int k = 0; k < 8; ++k) o[k] = f2h(s0[k]);
        *(ushort8v*)&Gh[(size_t)wid * 128 + cb] = o;
    }
}

// ---------------------------------------------------------------------------
// MFMA GEMM, direct-global operands, sliced stats epilogue.
//   AMODE 0: plain; 1: relu(a*x+b); 2: fused combine; RSC: bias*rowscale
// grid 625 x 256 thr; wave = 16 rows x 128 cols.
// ---------------------------------------------------------------------------
template<int AMODE, bool RSC>
__global__ __launch_bounds__(256) void mfma_gemm_kernel(
    const unsigned short* __restrict__ A, const unsigned short* __restrict__ A2,
    const unsigned short* __restrict__ Wt,
    const float* __restrict__ bias, const float* __restrict__ rowscale,
    const float* __restrict__ st1, const float* __restrict__ g1, const float* __restrict__ bt1,
    const float* __restrict__ st2, const float* __restrict__ g2, const float* __restrict__ bt2,
    const float* __restrict__ sN, const float* __restrict__ cN,
    const float* __restrict__ scal,
    const float* __restrict__ We, const float* __restrict__ Be,
    const float* __restrict__ ge, const float* __restrict__ bte,
    unsigned short* __restrict__ Out, float* __restrict__ stats_out)
{
    __shared__ float C1[128], D1[128], C2[128], D2[128];
    __shared__ float AE[128], BE[128], CE[128];
    __shared__ float redS[4][128], redQ[4][128];
    const int t = threadIdx.x;
    const int row0 = blockIdx.x * 64;

    if (AMODE >= 1) {
        bn_prep(st1, g1, bt1, C1, D1, t);
    }
    if (AMODE == 2) {
        bn_prep(st2, g2, bt2, C2, D2, t);
        if (t < 128) {
            float ms = scal[0] * RCP_N, vs = scal[1] * RCP_N - ms * ms;
            float mc = scal[2] * RCP_N, vc = scal[3] * RCP_N - mc * mc;
            float cov = scal[4] * RCP_N - ms * mc;
            float we = We[t], be = Be[t];
            float me = ms * we + mc * be;
            float ve = we * we * vs + be * be * vc + 2.f * we * be * cov;
            float ae = ge[t] * rsqrtf(ve + BN_EPS);
            AE[t] = we * ae; BE[t] = be * ae; CE[t] = bte[t] - me * ae;
        }
    }
    if (AMODE >= 1) __syncthreads();

    const int w = t >> 6, lane = t & 63;
    const int la = lane & 15, lb = lane >> 4;
    const int ar = row0 + (w << 4) + la;
    const int kb = lb * 8;

    f16x8v afrag[4];
    #pragma unroll
    for (int s = 0; s < 4; ++s) {
        ushort8v avv = *(const ushort8v*)&A[(size_t)ar * 128 + s * 32 + kb];
        if (AMODE == 0) {
            afrag[s] = __builtin_bit_cast(f16x8v, avv);
        } else if (AMODE == 1) {
            f16x8v o;
            #pragma unroll
            for (int j = 0; j < 8; ++j) {
                int qq = s * 32 + kb + j;
                o[j] = (_Float16)fmaxf(0.f, fmaf(h2f(avv[j]), C1[qq], D1[qq]));
            }
            afrag[s] = o;
        } else {
            ushort8v gv = *(const ushort8v*)&A2[(size_t)ar * 128 + s * 32 + kb];
            float sr = sN[ar], cr = cN[ar];
            f16x8v o;
            #pragma unroll
            for (int j = 0; j < 8; ++j) {
                int qq = s * 32 + kb + j;
                float y = h2f(avv[j]) * C1[qq] + D1[qq] + h2f(gv[j]) * C2[qq] + D2[qq]
                        + sr * AE[qq] + cr * BE[qq] + CE[qq];
                o[j] = (_Float16)fmaxf(0.f, y);
            }
            afrag[s] = o;
        }
    }
    // in-place safety: all A/A2 reads of this 64-row block complete before
    // any epilogue write (vmcnt drained before s_barrier)
    __syncthreads();

    f32x4v acc[8];
    #pragma unroll
    for (int c = 0; c < 8; ++c) acc[c] = (f32x4v){0.f, 0.f, 0.f, 0.f};

    #pragma unroll
    for (int c = 0; c < 8; ++c) {
        int bn_ = (c << 4) + la;
        #pragma unroll
        for (int s = 0; s < 4; ++s) {
            ushort8v bw = *(const ushort8v*)&Wt[(size_t)bn_ * 128 + s * 32 + kb];
            acc[c] = __builtin_amdgcn_mfma_f32_16x16x32_f16(
                afrag[s], __builtin_bit_cast(f16x8v, bw), acc[c], 0, 0, 0);
        }
    }

    const int orow0 = row0 + (w << 4) + lb * 4;
    float rsj[4];
    if (RSC) {
        #pragma unroll
        for (int j = 0; j < 4; ++j) rsj[j] = rowscale[orow0 + j];
    }
    float csum[8], csq[8];
    #pragma unroll
    for (int c = 0; c < 8; ++c) {
        int col = (c << 4) + la;
        float bc = bias[col];
        float s0 = 0.f, s1 = 0.f;
        #pragma unroll
        for (int j = 0; j < 4; ++j) {
            float v = acc[c][j] + (RSC ? rsj[j] * bc : bc);
            Out[(size_t)(orow0 + j) * 128 + col] = f2h(v);
            s0 += v; s1 += v * v;
        }
        csum[c] = s0; csq[c] = s1;
    }
    #pragma unroll
    for (int c = 0; c < 8; ++c) {
        csum[c] += __shfl_xor(csum[c], 16);
        csum[c] += __shfl_xor(csum[c], 32);
        csq[c]  += __shfl_xor(csq[c], 16);
        csq[c]  += __shfl_xor(csq[c], 32);
    }
    if (lane < 16) {
        #pragma unroll
        for (int c = 0; c < 8; ++c) {
            redS[w][(c << 4) + lane] = csum[c];
            redQ[w][(c << 4) + lane] = csq[c];
        }
    }
    __syncthreads();
    float* stS = stats_out + (blockIdx.x & (NSLICE - 1)) * 256;
    if (t < 128) {
        atomicAdd(&stS[t], redS[0][t] + redS[1][t] + redS[2][t] + redS[3][t]);
        atomicAdd(&stS[128 + t], redQ[0][t] + redQ[1][t] + redQ[2][t] + redQ[3][t]);
    }
}

// Final elementwise: out(f32) = relu(bn(Z f16)), sliced stats input
__global__ __launch_bounds__(256) void bnrelu_kernel(
    const unsigned short* __restrict__ Z, const float* __restrict__ stz,
    const float* __restrict__ g, const float* __restrict__ bt,
    float* __restrict__ O)
{
    __shared__ float aT[128], bT[128];
    int t = threadIdx.x;
    bn_prep(stz, g, bt, aT, bT, t);
    __syncthreads();
    int stride = gridDim.x * 256;
    for (int idx = blockIdx.x * 256 + t; idx < N_NODES * 32; idx += stride) {
        int r = idx >> 5;
        int q = (idx & 31) * 4;
        ushort4 z = *(const ushort4*)&Z[(size_t)r * 128 + q];
        float4 o;
        o.x = fmaxf(0.f, fmaf(h2f(z.x), aT[q],     bT[q]));
        o.y = fmaxf(0.f, fmaf(h2f(z.y), aT[q + 1], bT[q + 1]));
        o.z = fmaxf(0.f, fmaf(h2f(z.z), aT[q + 2], bT[q + 2]));
        o.w = fmaxf(0.f, fmaf(h2f(z.w), aT[q + 3], bT[q + 3]));
        *(float4*)&O[(size_t)r * 128 + q] = o;
    }
}

// ---------------------------------------------------------------------------
extern "C" void kernel_launch(void* const* d_in, const int* in_sizes, int n_in,
                              void* d_out, int out_size, void* d_ws, size_t ws_size,
                              hipStream_t stream)
{
    const float* node_attr = (const float*)d_in[0];
    const int*   ei        = (const int*)d_in[1];
    const float* ea        = (const float*)d_in[2];
    const float* W0    = (const float*)d_in[3];
    const float* b0    = (const float*)d_in[4];
    const float* g0    = (const float*)d_in[5];
    const float* bt0   = (const float*)d_in[6];
    const float* Wnode = (const float*)d_in[7];
    const float* bnode = (const float*)d_in[8];
    const float* Wedge = (const float*)d_in[9];
    const float* bedge = (const float*)d_in[10];
    const float* Wnb   = (const float*)d_in[11];
    const float* bnb   = (const float*)d_in[12];
    const float* gn    = (const float*)d_in[13];
    const float* ge    = (const float*)d_in[14];
    const float* gnb   = (const float*)d_in[15];
    const float* gm1   = (const float*)d_in[16];
    const float* gm2   = (const float*)d_in[17];
    const float* btn   = (const float*)d_in[18];
    const float* bte   = (const float*)d_in[19];
    const float* btnb  = (const float*)d_in[20];
    const float* btm1  = (const float*)d_in[21];
    const float* btm2  = (const float*)d_in[22];
    const float* Wm1   = (const float*)d_in[23];
    const float* bm1   = (const float*)d_in[24];
    const float* Wm2   = (const float*)d_in[25];
    const float* bm2   = (const float*)d_in[26];
    float* out = (float*)d_out;

    // workspace: Ph|ZNh|Gh (f16, NF each) | sN|cN|dg (f32) | st(sliced stats)
    //            | scP(u64,N) | cursor(u32,N) | slot(int, N*CAP) | Wtb(f16)
    unsigned short* Ph  = (unsigned short*)d_ws;
    unsigned short* ZNh = Ph + NF;
    unsigned short* Gh  = ZNh + NF;
    float* sN = (float*)(Gh + NF);
    float* cN = sN + N_NODES;
    float* dg = cN + N_NODES;
    float* st = dg + N_NODES;
    // st layout: [0..4] moments | [256..256+STB) init stats |
    //            layer i stat j at 256+STB + (i*4+j)*STB  (j: zn,aggr,z1,z2)
    const size_t ST_FLOATS = 256 + (size_t)STB * 13;
    unsigned long long* scP = (unsigned long long*)(st + ST_FLOATS);
    unsigned* cursor = (unsigned*)(scP + N_NODES);
    int* slot = (int*)(cursor + N_NODES);
    unsigned short* Wtb = (unsigned short*)(slot + (size_t)N_NODES * CAP);
    float* stInit = st + 256;
    float* layBase = st + 256 + STB;

    // zero st | scP | cursor (contiguous)
    (void)hipMemsetAsync(st, 0, (ST_FLOATS + 3 * (size_t)N_NODES) * sizeof(float), stream);
    wprep_kernel<<<48, 256, 0, stream>>>(Wnode, Wnb, Wm1, Wm2, Wtb);
    edge_slot_kernel<<<2500, 256, 0, stream>>>(ei, ea, scP, cursor, slot);
    decode_kernel<<<157, 256, 0, stream>>>(scP, cursor, sN, cN, dg, st);
    init_node_kernel<<<625, 256, 0, stream>>>(node_attr, W0, b0, Ph, stInit);

    const float* xst = stInit;
    const float* xg  = g0;
    const float* xbt = bt0;

    for (int i = 0; i < 3; ++i) {
        float* lay = layBase + (size_t)i * 4 * STB;
        // G = sum over in-neighbors of relu(bn(P[src]))
        gather_bn_kernel<<<10000, 256, 0, stream>>>(cursor, slot, Ph, xst, xg, xbt, Gh);
        // node branch: ZN = relu(bn(P)) @ Wnode + bnode (+stats)
        mfma_gemm_kernel<1, false><<<625, 256, 0, stream>>>(
            Ph, nullptr, Wtb + (size_t)(0 + i) * 16384, bnode + i * 128, nullptr,
            xst, xg, xbt, nullptr, nullptr, nullptr,
            nullptr, nullptr, nullptr, nullptr, nullptr, nullptr, nullptr,
            ZNh, lay);
        // neighbor branch: G = G @ Wnb + deg*bnb (+stats), in place
        mfma_gemm_kernel<0, true><<<625, 256, 0, stream>>>(
            Gh, nullptr, Wtb + (size_t)(3 + i) * 16384, bnb + i * 128, dg,
            nullptr, nullptr, nullptr, nullptr, nullptr, nullptr,
            nullptr, nullptr, nullptr, nullptr, nullptr, nullptr, nullptr,
            Gh, lay + STB);
        // z1 = relu(bn(ZN)+bn(G)+ea) @ Wm1 + bm1 (+stats) -> ZN (fused combine)
        mfma_gemm_kernel<2, false><<<625, 256, 0, stream>>>(
            ZNh, Gh, Wtb + (size_t)(6 + i) * 16384, bm1 + i * 128, nullptr,
            lay, gn + i * 128, btn + i * 128,
            lay + STB, gnb + i * 128, btnb + i * 128,
            sN, cN, st,
            Wedge + i * 128, bedge + i * 128, ge + i * 128, bte + i * 128,
            ZNh, lay + 2 * STB);
        // z2 = relu(bn(z1)) @ Wm2 + bm2 (+stats) -> P
        mfma_gemm_kernel<1, false><<<625, 256, 0, stream>>>(
            ZNh, nullptr, Wtb + (size_t)(9 + i) * 16384, bm2 + i * 128, nullptr,
            lay + 2 * STB, gm1 + i * 128, btm1 + i * 128, nullptr, nullptr, nullptr,
            nullptr, nullptr, nullptr, nullptr, nullptr, nullptr, nullptr,
            Ph, lay + 3 * STB);

        xst = lay + 3 * STB;
        xg  = gm2 + i * 128;
        xbt = btm2 + i * 128;
    }
    bnrelu_kernel<<<2048, 256, 0, stream>>>(Ph, xst, xg, xbt, out);
}

// Round 11
// 404.487 us; speedup vs baseline: 1.6161x; 1.0604x over previous
//
#include <hip/hip_runtime.h>

#define N_NODES 40000
#define N_EDGES 640000
#define EMB 128
#define NF ((size_t)N_NODES * EMB)
#define RCP_N (1.0f / (float)N_NODES)
#define BN_EPS 1e-5f
#define CAP 64          // fixed bucket capacity (avg deg 16; P(>64) ~ 1e-18)
#define NSLICE 16       // stats accumulator slices (atomic contention fix)
#define STB (NSLICE * 256)   // floats per sliced stat block
#define GB 1250         // GEMM grid: 32-row tiles

typedef _Float16 f16x8v __attribute__((ext_vector_type(8)));
typedef float f32x4v __attribute__((ext_vector_type(4)));
typedef unsigned short ushort8v __attribute__((ext_vector_type(8)));

__device__ __forceinline__ unsigned short f2h(float v) {
    return __builtin_bit_cast(unsigned short, (_Float16)v);
}
__device__ __forceinline__ float h2f(unsigned short u) {
    return (float)__builtin_bit_cast(_Float16, u);
}

// Sum NSLICE slices of a stat block -> bn scale/shift (threads t<128)
__device__ __forceinline__ void bn_prep(
    const float* __restrict__ stat, const float* __restrict__ g,
    const float* __restrict__ bt, float* C, float* D, int t)
{
    if (t < 128) {
        float sm = 0.f, sq = 0.f;
        #pragma unroll
        for (int s = 0; s < NSLICE; ++s) {
            sm += stat[s * 256 + t];
            sq += stat[s * 256 + 128 + t];
        }
        float m = sm * RCP_N;
        float v = sq * RCP_N - m * m;
        float a = g[t] * rsqrtf(v + BN_EPS);
        C[t] = a; D[t] = bt[t] - m * a;
    }
}

// ---------------------------------------------------------------------------
// Per-edge pass (1 edge/thread = max outstanding atomics)
// ---------------------------------------------------------------------------
__global__ __launch_bounds__(256) void edge_slot_kernel(
    const int* __restrict__ ei, const float* __restrict__ ea,
    unsigned long long* __restrict__ scP, unsigned* __restrict__ cursor,
    int* __restrict__ slot)
{
    int e = blockIdx.x * 256 + threadIdx.x;   // grid = 2500*256 == N_EDGES
    int r = ei[e];
    int d = ei[N_EDGES + e];
    int fx = (int)rintf(ea[e] * 65536.0f);
    unsigned long long add =
        (((unsigned long long)(unsigned)(fx + 0x40000000)) << 20) | 1ULL;
    atomicAdd(&scP[r], add);
    unsigned pos = atomicAdd(&cursor[d], 1u);
    slot[(size_t)d * CAP + (pos < CAP ? pos : CAP - 1)] = r;
}

// Decode scP -> sN, cN + scalar moments; cursor -> f32 deg.  grid 157
__global__ __launch_bounds__(256) void decode_kernel(
    const unsigned long long* __restrict__ scP, const unsigned* __restrict__ cursor,
    float* __restrict__ sN, float* __restrict__ cN, float* __restrict__ dgf,
    float* __restrict__ mom)
{
    int t = threadIdx.x;
    int i = blockIdx.x * 256 + t;
    float a0 = 0.f, a1 = 0.f, a2 = 0.f, a3 = 0.f, a4 = 0.f;
    if (i < N_NODES) {
        unsigned long long v = scP[i];
        unsigned cnt = (unsigned)(v & 0xFFFFFULL);
        long long sp = (long long)(v >> 20) - ((long long)cnt << 30);
        float s = (float)sp * (1.0f / 65536.0f);
        float c = (float)cnt;
        sN[i] = s; cN[i] = c;
        dgf[i] = (float)cursor[i];
        a0 = s; a1 = s * s; a2 = c; a3 = c * c; a4 = s * c;
    }
    #pragma unroll
    for (int off = 32; off > 0; off >>= 1) {
        a0 += __shfl_down(a0, off);
        a1 += __shfl_down(a1, off);
        a2 += __shfl_down(a2, off);
        a3 += __shfl_down(a3, off);
        a4 += __shfl_down(a4, off);
    }
    if ((t & 63) == 0) {
        atomicAdd(&mom[0], a0);
        atomicAdd(&mom[1], a1);
        atomicAdd(&mom[2], a2);
        atomicAdd(&mom[3], a3);
        atomicAdd(&mom[4], a4);
    }
}

// ---------------------------------------------------------------------------
// Initial node MLP: P(f16) = node_attr @ W0 + b0 (K=2), sliced col stats
// ---------------------------------------------------------------------------
__global__ __launch_bounds__(256) void init_node_kernel(
    const float* __restrict__ na, const float* __restrict__ W0,
    const float* __restrict__ b0, unsigned short* __restrict__ Z,
    float* __restrict__ st)
{
    int t = threadIdx.x;
    int col = t & 127, rh = t >> 7;
    float w0 = W0[col], w1 = W0[128 + col], bb = b0[col];
    int rbase = blockIdx.x * 64;
    float sm = 0.f, sq = 0.f;
    #pragma unroll 4
    for (int i = 0; i < 32; ++i) {
        int r = rbase + rh + i * 2;
        float2 nv = *(const float2*)&na[r * 2];
        float v = fmaf(nv.x, w0, fmaf(nv.y, w1, bb));
        Z[(size_t)r * 128 + col] = f2h(v);
        sm += v; sq += v * v;
    }
    __shared__ float red[256];
    float* stS = st + (blockIdx.x & (NSLICE - 1)) * 256;
    red[t] = sm; __syncthreads();
    if (t < 128) atomicAdd(&stS[t], red[t] + red[t + 128]);
    __syncthreads();
    red[t] = sq; __syncthreads();
    if (t < 128) atomicAdd(&stS[128 + t], red[t] + red[t + 128]);
}

// ---------------------------------------------------------------------------
// Weight prep: Wt[mat][n][k] = f16(W[mat][k][n]), 12 matrices of 128x128.
// ---------------------------------------------------------------------------
__global__ __launch_bounds__(256) void wprep_kernel(
    const float* __restrict__ Wnode, const float* __restrict__ Wnb,
    const float* __restrict__ Wm1, const float* __restrict__ Wm2,
    unsigned short* __restrict__ Wt)
{
    __shared__ float tile[32][129];
    int b = blockIdx.x;
    int mat = b >> 2, kc = (b & 3) * 32;
    int grp = mat / 3, lay = mat % 3;
    const float* src = (grp == 0) ? Wnode : (grp == 1) ? Wnb : (grp == 2) ? Wm1 : Wm2;
    src += (size_t)lay * 16384;
    int t = threadIdx.x;
    #pragma unroll
    for (int i = 0; i < 16; ++i) {
        int idx = t + i * 256;
        int r = idx >> 7, n = idx & 127;
        tile[r][n] = src[(size_t)(kc + r) * 128 + n];
    }
    __syncthreads();
    int n = t >> 1, h = (t & 1) * 16;
    ushort8v o0, o1;
    #pragma unroll
    for (int j = 0; j < 8; ++j) o0[j] = f2h(tile[h + j][n]);
    #pragma unroll
    for (int j = 0; j < 8; ++j) o1[j] = f2h(tile[h + 8 + j][n]);
    unsigned short* dst = &Wt[(size_t)mat * 16384 + n * 128 + kc + h];
    *(ushort8v*)dst = o0;
    *(ushort8v*)(dst + 8) = o1;
}

// ---------------------------------------------------------------------------
// Gather with inline bn+relu: G[d] = sum relu(a*P[slot[d][j]]+b)
// Quarter-wave per row; 4 rows across quarters x 2-deep unroll.
// ---------------------------------------------------------------------------
__global__ __launch_bounds__(256) void gather_bn_kernel(
    const unsigned* __restrict__ cnt, const int* __restrict__ slot,
    const unsigned short* __restrict__ Ph,
    const float* __restrict__ stat, const float* __restrict__ g_in,
    const float* __restrict__ bt_in,
    unsigned short* __restrict__ Gh)
{
    __shared__ float aT[128], bT[128];
    int t = threadIdx.x;
    bn_prep(stat, g_in, bt_in, aT, bT, t);
    __syncthreads();
    int wid = (blockIdx.x * 256 + t) >> 6;   // grid 10000 -> 40000 waves
    int lane = t & 63;
    int q = lane >> 4, l16 = lane & 15;
    int cb = l16 * 8;
    float av[8], bv[8];
    #pragma unroll
    for (int k = 0; k < 8; ++k) { av[k] = aT[cb + k]; bv[k] = bT[cb + k]; }
    int n = (int)cnt[wid];
    n = n < CAP ? n : CAP;
    const int* sl = &slot[(size_t)wid * CAP];
    float s0[8] = {0}, s1[8] = {0};
    int j = q;
    for (; j + 4 < n; j += 8) {
        int r0 = sl[j], r1 = sl[j + 4];
        ushort8v v0 = *(const ushort8v*)&Ph[(size_t)r0 * 128 + cb];
        ushort8v v1 = *(const ushort8v*)&Ph[(size_t)r1 * 128 + cb];
        #pragma unroll
        for (int k = 0; k < 8; ++k) {
            s0[k] += fmaxf(0.f, fmaf(h2f(v0[k]), av[k], bv[k]));
            s1[k] += fmaxf(0.f, fmaf(h2f(v1[k]), av[k], bv[k]));
        }
    }
    for (; j < n; j += 4) {
        int r0 = sl[j];
        ushort8v v0 = *(const ushort8v*)&Ph[(size_t)r0 * 128 + cb];
        #pragma unroll
        for (int k = 0; k < 8; ++k)
            s0[k] += fmaxf(0.f, fmaf(h2f(v0[k]), av[k], bv[k]));
    }
    #pragma unroll
    for (int k = 0; k < 8; ++k) {
        float v = s0[k] + s1[k];
        v += __shfl_xor(v, 16);
        v += __shfl_xor(v, 32);
        s0[k] = v;
    }
    if (q == 0) {
        ushort8v o;
        #pragma unroll
        for (int k = 0; k < 8; ++k) o[k] = f2h(s0[k]);
        *(ushort8v*)&Gh[(size_t)wid * 128 + cb] = o;
    }
}

// ---------------------------------------------------------------------------
// GEMM body: 32-row tile, 128 threads (2 waves), direct-global operands,
// f16 in/out, f32 accum, sliced stats epilogue.
// ---------------------------------------------------------------------------
template<int AMODE, bool RSC>
__device__ __forceinline__ void gemm32_body(
    int row0, int t, int slice,
    const unsigned short* __restrict__ A, const unsigned short* __restrict__ A2,
    const unsigned short* __restrict__ Wt,
    const float* __restrict__ bias, const float* __restrict__ rowscale,
    const float* C1, const float* D1, const float* C2, const float* D2,
    const float* AE, const float* BE, const float* CE,
    const float* __restrict__ sN, const float* __restrict__ cN,
    unsigned short* __restrict__ Out, float* __restrict__ stats_out,
    float (*redS)[128], float (*redQ)[128])
{
    const int w = t >> 6, lane = t & 63;
    const int la = lane & 15, lb = lane >> 4;
    const int ar = row0 + (w << 4) + la;
    const int kb = lb * 8;

    f16x8v afrag[4];
    #pragma unroll
    for (int s = 0; s < 4; ++s) {
        ushort8v avv = *(const ushort8v*)&A[(size_t)ar * 128 + s * 32 + kb];
        if (AMODE == 0) {
            afrag[s] = __builtin_bit_cast(f16x8v, avv);
        } else if (AMODE == 1) {
            f16x8v o;
            #pragma unroll
            for (int j = 0; j < 8; ++j) {
                int qq = s * 32 + kb + j;
                o[j] = (_Float16)fmaxf(0.f, fmaf(h2f(avv[j]), C1[qq], D1[qq]));
            }
            afrag[s] = o;
        } else {
            ushort8v gv = *(const ushort8v*)&A2[(size_t)ar * 128 + s * 32 + kb];
            float sr = sN[ar], cr = cN[ar];
            f16x8v o;
            #pragma unroll
            for (int j = 0; j < 8; ++j) {
                int qq = s * 32 + kb + j;
                float y = h2f(avv[j]) * C1[qq] + D1[qq] + h2f(gv[j]) * C2[qq] + D2[qq]
                        + sr * AE[qq] + cr * BE[qq] + CE[qq];
                o[j] = (_Float16)fmaxf(0.f, y);
            }
            afrag[s] = o;
        }
    }
    // in-place safety: all A/A2 reads of this 32-row tile complete before
    // any epilogue write (vmcnt drained before s_barrier)
    __syncthreads();

    f32x4v acc[8];
    #pragma unroll
    for (int c = 0; c < 8; ++c) acc[c] = (f32x4v){0.f, 0.f, 0.f, 0.f};

    #pragma unroll
    for (int c = 0; c < 8; ++c) {
        int bn_ = (c << 4) + la;
        #pragma unroll
        for (int s = 0; s < 4; ++s) {
            ushort8v bw = *(const ushort8v*)&Wt[(size_t)bn_ * 128 + s * 32 + kb];
            acc[c] = __builtin_amdgcn_mfma_f32_16x16x32_f16(
                afrag[s], __builtin_bit_cast(f16x8v, bw), acc[c], 0, 0, 0);
        }
    }

    const int orow0 = row0 + (w << 4) + lb * 4;
    float rsj[4];
    if (RSC) {
        #pragma unroll
        for (int j = 0; j < 4; ++j) rsj[j] = rowscale[orow0 + j];
    }
    float csum[8], csq[8];
    #pragma unroll
    for (int c = 0; c < 8; ++c) {
        int col = (c << 4) + la;
        float bc = bias[col];
        float s0 = 0.f, s1 = 0.f;
        #pragma unroll
        for (int j = 0; j < 4; ++j) {
            float v = acc[c][j] + (RSC ? rsj[j] * bc : bc);
            Out[(size_t)(orow0 + j) * 128 + col] = f2h(v);
            s0 += v; s1 += v * v;
        }
        csum[c] = s0; csq[c] = s1;
    }
    #pragma unroll
    for (int c = 0; c < 8; ++c) {
        csum[c] += __shfl_xor(csum[c], 16);
        csum[c] += __shfl_xor(csum[c], 32);
        csq[c]  += __shfl_xor(csq[c], 16);
        csq[c]  += __shfl_xor(csq[c], 32);
    }
    if (lane < 16) {
        #pragma unroll
        for (int c = 0; c < 8; ++c) {
            redS[w][(c << 4) + lane] = csum[c];
            redQ[w][(c << 4) + lane] = csq[c];
        }
    }
    __syncthreads();
    float* stS = stats_out + slice * 256;
    if (t < 128) {
        atomicAdd(&stS[t], redS[0][t] + redS[1][t]);
        atomicAdd(&stS[128 + t], redQ[0][t] + redQ[1][t]);
    }
}

// ---------------------------------------------------------------------------
// Dual GEMM: blocks [0,GB) node branch (AMODE1), [GB,2GB) neighbor (AMODE0+RSC)
// ---------------------------------------------------------------------------
__global__ __launch_bounds__(128) void dual_gemm_kernel(
    const unsigned short* __restrict__ Ph, unsigned short* __restrict__ Gh,
    const unsigned short* __restrict__ WtZ, const unsigned short* __restrict__ WtG,
    const float* __restrict__ bZ, const float* __restrict__ bG,
    const float* __restrict__ dg,
    const float* __restrict__ st1, const float* __restrict__ g1,
    const float* __restrict__ bt1,
    unsigned short* __restrict__ ZNh,
    float* __restrict__ statZN, float* __restrict__ statG)
{
    __shared__ float C1[128], D1[128];
    __shared__ float redS[2][128], redQ[2][128];
    const int t = threadIdx.x;
    const int b = blockIdx.x;

    if (b < GB) {
        bn_prep(st1, g1, bt1, C1, D1, t);
        __syncthreads();
        gemm32_body<1, false>(b * 32, t, b & (NSLICE - 1),
            Ph, nullptr, WtZ, bZ, nullptr,
            C1, D1, nullptr, nullptr, nullptr, nullptr, nullptr,
            nullptr, nullptr, ZNh, statZN, redS, redQ);
    } else {
        gemm32_body<0, true>((b - GB) * 32, t, b & (NSLICE - 1),
            Gh, nullptr, WtG, bG, dg,
            nullptr, nullptr, nullptr, nullptr, nullptr, nullptr, nullptr,
            nullptr, nullptr, Gh, statG, redS, redQ);
    }
}

// ---------------------------------------------------------------------------
// Standalone GEMM (32-row tiles). grid GB x 128 thr.
// ---------------------------------------------------------------------------
template<int AMODE, bool RSC>
__global__ __launch_bounds__(128) void mfma_gemm_kernel(
    const unsigned short* __restrict__ A, const unsigned short* __restrict__ A2,
    const unsigned short* __restrict__ Wt,
    const float* __restrict__ bias, const float* __restrict__ rowscale,
    const float* __restrict__ st1, const float* __restrict__ g1, const float* __restrict__ bt1,
    const float* __restrict__ st2, const float* __restrict__ g2, const float* __restrict__ bt2,
    const float* __restrict__ sN, const float* __restrict__ cN,
    const float* __restrict__ scal,
    const float* __restrict__ We, const float* __restrict__ Be,
    const float* __restrict__ ge, const float* __restrict__ bte,
    unsigned short* __restrict__ Out, float* __restrict__ stats_out)
{
    __shared__ float C1[128], D1[128], C2[128], D2[128];
    __shared__ float AE[128], BE[128], CE[128];
    __shared__ float redS[2][128], redQ[2][128];
    const int t = threadIdx.x;

    if (AMODE >= 1) {
        bn_prep(st1, g1, bt1, C1, D1, t);
    }
    if (AMODE == 2) {
        bn_prep(st2, g2, bt2, C2, D2, t);
        if (t < 128) {
            float ms = scal[0] * RCP_N, vs = scal[1] * RCP_N - ms * ms;
            float mc = scal[2] * RCP_N, vc = scal[3] * RCP_N - mc * mc;
            float cov = scal[4] * RCP_N - ms * mc;
            float we = We[t], be = Be[t];
            float me = ms * we + mc * be;
            float ve = we * we * vs + be * be * vc + 2.f * we * be * cov;
            float ae = ge[t] * rsqrtf(ve + BN_EPS);
            AE[t] = we * ae; BE[t] = be * ae; CE[t] = bte[t] - me * ae;
        }
    }
    if (AMODE >= 1) __syncthreads();

    gemm32_body<AMODE, RSC>(blockIdx.x * 32, t, blockIdx.x & (NSLICE - 1),
        A, A2, Wt, bias, rowscale,
        C1, D1, C2, D2, AE, BE, CE,
        sN, cN, Out, stats_out, redS, redQ);
}

// Final elementwise: out(f32) = relu(bn(Z f16)), sliced stats input
__global__ __launch_bounds__(256) void bnrelu_kernel(
    const unsigned short* __restrict__ Z, const float* __restrict__ stz,
    const float* __restrict__ g, const float* __restrict__ bt,
    float* __restrict__ O)
{
    __shared__ float aT[128], bT[128];
    int t = threadIdx.x;
    bn_prep(stz, g, bt, aT, bT, t);
    __syncthreads();
    int stride = gridDim.x * 256;
    for (int idx = blockIdx.x * 256 + t; idx < N_NODES * 32; idx += stride) {
        int r = idx >> 5;
        int q = (idx & 31) * 4;
        ushort4 z = *(const ushort4*)&Z[(size_t)r * 128 + q];
        float4 o;
        o.x = fmaxf(0.f, fmaf(h2f(z.x), aT[q],     bT[q]));
        o.y = fmaxf(0.f, fmaf(h2f(z.y), aT[q + 1], bT[q + 1]));
        o.z = fmaxf(0.f, fmaf(h2f(z.z), aT[q + 2], bT[q + 2]));
        o.w = fmaxf(0.f, fmaf(h2f(z.w), aT[q + 3], bT[q + 3]));
        *(float4*)&O[(size_t)r * 128 + q] = o;
    }
}

// ---------------------------------------------------------------------------
extern "C" void kernel_launch(void* const* d_in, const int* in_sizes, int n_in,
                              void* d_out, int out_size, void* d_ws, size_t ws_size,
                              hipStream_t stream)
{
    const float* node_attr = (const float*)d_in[0];
    const int*   ei        = (const int*)d_in[1];
    const float* ea        = (const float*)d_in[2];
    const float* W0    = (const float*)d_in[3];
    const float* b0    = (const float*)d_in[4];
    const float* g0    = (const float*)d_in[5];
    const float* bt0   = (const float*)d_in[6];
    const float* Wnode = (const float*)d_in[7];
    const float* bnode = (const float*)d_in[8];
    const float* Wedge = (const float*)d_in[9];
    const float* bedge = (const float*)d_in[10];
    const float* Wnb   = (const float*)d_in[11];
    const float* bnb   = (const float*)d_in[12];
    const float* gn    = (const float*)d_in[13];
    const float* ge    = (const float*)d_in[14];
    const float* gnb   = (const float*)d_in[15];
    const float* gm1   = (const float*)d_in[16];
    const float* gm2   = (const float*)d_in[17];
    const float* btn   = (const float*)d_in[18];
    const float* bte   = (const float*)d_in[19];
    const float* btnb  = (const float*)d_in[20];
    const float* btm1  = (const float*)d_in[21];
    const float* btm2  = (const float*)d_in[22];
    const float* Wm1   = (const float*)d_in[23];
    const float* bm1   = (const float*)d_in[24];
    const float* Wm2   = (const float*)d_in[25];
    const float* bm2   = (const float*)d_in[26];
    float* out = (float*)d_out;

    // workspace: Ph|ZNh|Gh (f16, NF each) | sN|cN|dg (f32) | st(sliced stats)
    //            | scP(u64,N) | cursor(u32,N) | slot(int, N*CAP) | Wtb(f16)
    unsigned short* Ph  = (unsigned short*)d_ws;
    unsigned short* ZNh = Ph + NF;
    unsigned short* Gh  = ZNh + NF;
    float* sN = (float*)(Gh + NF);
    float* cN = sN + N_NODES;
    float* dg = cN + N_NODES;
    float* st = dg + N_NODES;
    // st layout: [0..4] moments | [256..256+STB) init stats |
    //            layer i stat j at 256+STB + (i*4+j)*STB  (j: zn,aggr,z1,z2)
    const size_t ST_FLOATS = 256 + (size_t)STB * 13;
    unsigned long long* scP = (unsigned long long*)(st + ST_FLOATS);
    unsigned* cursor = (unsigned*)(scP + N_NODES);
    int* slot = (int*)(cursor + N_NODES);
    unsigned short* Wtb = (unsigned short*)(slot + (size_t)N_NODES * CAP);
    float* stInit = st + 256;
    float* layBase = st + 256 + STB;

    // zero st | scP | cursor (contiguous)
    (void)hipMemsetAsync(st, 0, (ST_FLOATS + 3 * (size_t)N_NODES) * sizeof(float), stream);
    wprep_kernel<<<48, 256, 0, stream>>>(Wnode, Wnb, Wm1, Wm2, Wtb);
    edge_slot_kernel<<<2500, 256, 0, stream>>>(ei, ea, scP, cursor, slot);
    decode_kernel<<<157, 256, 0, stream>>>(scP, cursor, sN, cN, dg, st);
    init_node_kernel<<<625, 256, 0, stream>>>(node_attr, W0, b0, Ph, stInit);

    const float* xst = stInit;
    const float* xg  = g0;
    const float* xbt = bt0;

    for (int i = 0; i < 3; ++i) {
        float* lay = layBase + (size_t)i * 4 * STB;
        // G = sum over in-neighbors of relu(bn(P[src]))
        gather_bn_kernel<<<10000, 256, 0, stream>>>(cursor, slot, Ph, xst, xg, xbt, Gh);
        // dual: ZN = relu(bn(P)) @ Wnode + bnode  ||  G = G @ Wnb + deg*bnb
        dual_gemm_kernel<<<2 * GB, 128, 0, stream>>>(
            Ph, Gh,
            Wtb + (size_t)(0 + i) * 16384, Wtb + (size_t)(3 + i) * 16384,
            bnode + i * 128, bnb + i * 128, dg,
            xst, xg, xbt,
            ZNh, lay, lay + STB);
        // z1 = relu(bn(ZN)+bn(G)+ea) @ Wm1 + bm1 (+stats) -> ZN (fused combine)
        mfma_gemm_kernel<2, false><<<GB, 128, 0, stream>>>(
            ZNh, Gh, Wtb + (size_t)(6 + i) * 16384, bm1 + i * 128, nullptr,
            lay, gn + i * 128, btn + i * 128,
            lay + STB, gnb + i * 128, btnb + i * 128,
            sN, cN, st,
            Wedge + i * 128, bedge + i * 128, ge + i * 128, bte + i * 128,
            ZNh, lay + 2 * STB);
        // z2 = relu(bn(z1)) @ Wm2 + bm2 (+stats) -> P
        mfma_gemm_kernel<1, false><<<GB, 128, 0, stream>>>(
            ZNh, nullptr, Wtb + (size_t)(9 + i) * 16384, bm2 + i * 128, nullptr,
            lay + 2 * STB, gm1 + i * 128, btm1 + i * 128, nullptr, nullptr, nullptr,
            nullptr, nullptr, nullptr, nullptr, nullptr, nullptr, nullptr,
            Ph, lay + 3 * STB);

        xst = lay + 3 * STB;
        xg  = gm2 + i * 128;
        xbt = btm2 + i * 128;
    }
    bnrelu_kernel<<<2048, 256, 0, stream>>>(Ph, xst, xg, xbt, out);
}

// Round 12
// 309.436 us; speedup vs baseline: 2.1126x; 1.3072x over previous
//
#include <hip/hip_runtime.h>

#define N_NODES 40000
#define N_EDGES 640000
#define EMB 128
#define NF ((size_t)N_NODES * EMB)
#define RCP_N (1.0f / (float)N_NODES)
#define BN_EPS 1e-5f
#define CAP 64          // fixed bucket capacity (avg deg 16; P(>64) ~ 1e-18)
#define NSLICE 16       // stats accumulator slices (atomic contention fix)
#define STB (NSLICE * 256)   // floats per sliced stat block
#define GB 625          // GEMM grid: 64-row tiles, 256 threads

typedef _Float16 f16x8v __attribute__((ext_vector_type(8)));
typedef float f32x4v __attribute__((ext_vector_type(4)));
typedef unsigned short ushort8v __attribute__((ext_vector_type(8)));

__device__ __forceinline__ unsigned short f2h(float v) {
    return __builtin_bit_cast(unsigned short, (_Float16)v);
}
__device__ __forceinline__ float h2f(unsigned short u) {
    return (float)__builtin_bit_cast(_Float16, u);
}

// Sum NSLICE slices of a stat block -> bn scale/shift (threads t<128)
__device__ __forceinline__ void bn_prep(
    const float* __restrict__ stat, const float* __restrict__ g,
    const float* __restrict__ bt, float* C, float* D, int t)
{
    if (t < 128) {
        float sm = 0.f, sq = 0.f;
        #pragma unroll
        for (int s = 0; s < NSLICE; ++s) {
            sm += stat[s * 256 + t];
            sq += stat[s * 256 + 128 + t];
        }
        float m = sm * RCP_N;
        float v = sq * RCP_N - m * m;
        float a = g[t] * rsqrtf(v + BN_EPS);
        C[t] = a; D[t] = bt[t] - m * a;
    }
}

// ---------------------------------------------------------------------------
// Merged edge pass + initial node MLP (independent roles; tiny LDS so edge
// occupancy is unhurt — lesson from R9's failed 17.9KB-LDS merge):
//   blocks [0,625): P(f16) = node_attr @ W0 + b0, sliced col stats
//   blocks [625,3125): per-edge atomics (1 edge/thread = max outstanding)
// ---------------------------------------------------------------------------
__global__ __launch_bounds__(256) void edge_init_kernel(
    const float* __restrict__ na, const float* __restrict__ W0,
    const float* __restrict__ b0, unsigned short* __restrict__ Z,
    float* __restrict__ st,
    const int* __restrict__ ei, const float* __restrict__ ea,
    unsigned long long* __restrict__ scP, unsigned* __restrict__ cursor,
    int* __restrict__ slot)
{
    __shared__ float red[256];
    const int blk = blockIdx.x;
    const int t = threadIdx.x;
    if (blk < 625) {
        int col = t & 127, rh = t >> 7;
        float w0 = W0[col], w1 = W0[128 + col], bb = b0[col];
        int rbase = blk * 64;
        float sm = 0.f, sq = 0.f;
        #pragma unroll 4
        for (int i = 0; i < 32; ++i) {
            int r = rbase + rh + i * 2;
            float2 nv = *(const float2*)&na[r * 2];
            float v = fmaf(nv.x, w0, fmaf(nv.y, w1, bb));
            Z[(size_t)r * 128 + col] = f2h(v);
            sm += v; sq += v * v;
        }
        float* stS = st + (blk & (NSLICE - 1)) * 256;
        red[t] = sm; __syncthreads();
        if (t < 128) atomicAdd(&stS[t], red[t] + red[t + 128]);
        __syncthreads();
        red[t] = sq; __syncthreads();
        if (t < 128) atomicAdd(&stS[128 + t], red[t] + red[t + 128]);
    } else {
        int e = (blk - 625) * 256 + t;     // 2500*256 == N_EDGES
        int r = ei[e];
        int d = ei[N_EDGES + e];
        int fx = (int)rintf(ea[e] * 65536.0f);
        unsigned long long add =
            (((unsigned long long)(unsigned)(fx + 0x40000000)) << 20) | 1ULL;
        atomicAdd(&scP[r], add);
        unsigned pos = atomicAdd(&cursor[d], 1u);
        slot[(size_t)d * CAP + (pos < CAP ? pos : CAP - 1)] = r;
    }
}

// Decode scP -> sN, cN + scalar moments; cursor -> f32 deg.  grid 157
__global__ __launch_bounds__(256) void decode_kernel(
    const unsigned long long* __restrict__ scP, const unsigned* __restrict__ cursor,
    float* __restrict__ sN, float* __restrict__ cN, float* __restrict__ dgf,
    float* __restrict__ mom)
{
    int t = threadIdx.x;
    int i = blockIdx.x * 256 + t;
    float a0 = 0.f, a1 = 0.f, a2 = 0.f, a3 = 0.f, a4 = 0.f;
    if (i < N_NODES) {
        unsigned long long v = scP[i];
        unsigned cnt = (unsigned)(v & 0xFFFFFULL);
        long long sp = (long long)(v >> 20) - ((long long)cnt << 30);
        float s = (float)sp * (1.0f / 65536.0f);
        float c = (float)cnt;
        sN[i] = s; cN[i] = c;
        dgf[i] = (float)cursor[i];
        a0 = s; a1 = s * s; a2 = c; a3 = c * c; a4 = s * c;
    }
    #pragma unroll
    for (int off = 32; off > 0; off >>= 1) {
        a0 += __shfl_down(a0, off);
        a1 += __shfl_down(a1, off);
        a2 += __shfl_down(a2, off);
        a3 += __shfl_down(a3, off);
        a4 += __shfl_down(a4, off);
    }
    if ((t & 63) == 0) {
        atomicAdd(&mom[0], a0);
        atomicAdd(&mom[1], a1);
        atomicAdd(&mom[2], a2);
        atomicAdd(&mom[3], a3);
        atomicAdd(&mom[4], a4);
    }
}

// ---------------------------------------------------------------------------
// Weight prep: Wt[mat][n][k] = f16(W[mat][k][n]), 12 matrices of 128x128.
// ---------------------------------------------------------------------------
__global__ __launch_bounds__(256) void wprep_kernel(
    const float* __restrict__ Wnode, const float* __restrict__ Wnb,
    const float* __restrict__ Wm1, const float* __restrict__ Wm2,
    unsigned short* __restrict__ Wt)
{
    __shared__ float tile[32][129];
    int b = blockIdx.x;
    int mat = b >> 2, kc = (b & 3) * 32;
    int grp = mat / 3, lay = mat % 3;
    const float* src = (grp == 0) ? Wnode : (grp == 1) ? Wnb : (grp == 2) ? Wm1 : Wm2;
    src += (size_t)lay * 16384;
    int t = threadIdx.x;
    #pragma unroll
    for (int i = 0; i < 16; ++i) {
        int idx = t + i * 256;
        int r = idx >> 7, n = idx & 127;
        tile[r][n] = src[(size_t)(kc + r) * 128 + n];
    }
    __syncthreads();
    int n = t >> 1, h = (t & 1) * 16;
    ushort8v o0, o1;
    #pragma unroll
    for (int j = 0; j < 8; ++j) o0[j] = f2h(tile[h + j][n]);
    #pragma unroll
    for (int j = 0; j < 8; ++j) o1[j] = f2h(tile[h + 8 + j][n]);
    unsigned short* dst = &Wt[(size_t)mat * 16384 + n * 128 + kc + h];
    *(ushort8v*)dst = o0;
    *(ushort8v*)(dst + 8) = o1;
}

// ---------------------------------------------------------------------------
// Gather with inline bn+relu: G[d] = sum relu(a*P[slot[d][j]]+b)
// Quarter-wave per row; 4 rows across quarters x 2-deep unroll.
// ---------------------------------------------------------------------------
__global__ __launch_bounds__(256) void gather_bn_kernel(
    const unsigned* __restrict__ cnt, const int* __restrict__ slot,
    const unsigned short* __restrict__ Ph,
    const float* __restrict__ stat, const float* __restrict__ g_in,
    const float* __restrict__ bt_in,
    unsigned short* __restrict__ Gh)
{
    __shared__ float aT[128], bT[128];
    int t = threadIdx.x;
    bn_prep(stat, g_in, bt_in, aT, bT, t);
    __syncthreads();
    int wid = (blockIdx.x * 256 + t) >> 6;   // grid 10000 -> 40000 waves
    int lane = t & 63;
    int q = lane >> 4, l16 = lane & 15;
    int cb = l16 * 8;
    float av[8], bv[8];
    #pragma unroll
    for (int k = 0; k < 8; ++k) { av[k] = aT[cb + k]; bv[k] = bT[cb + k]; }
    int n = (int)cnt[wid];
    n = n < CAP ? n : CAP;
    const int* sl = &slot[(size_t)wid * CAP];
    float s0[8] = {0}, s1[8] = {0};
    int j = q;
    for (; j + 4 < n; j += 8) {
        int r0 = sl[j], r1 = sl[j + 4];
        ushort8v v0 = *(const ushort8v*)&Ph[(size_t)r0 * 128 + cb];
        ushort8v v1 = *(const ushort8v*)&Ph[(size_t)r1 * 128 + cb];
        #pragma unroll
        for (int k = 0; k < 8; ++k) {
            s0[k] += fmaxf(0.f, fmaf(h2f(v0[k]), av[k], bv[k]));
            s1[k] += fmaxf(0.f, fmaf(h2f(v1[k]), av[k], bv[k]));
        }
    }
    for (; j < n; j += 4) {
        int r0 = sl[j];
        ushort8v v0 = *(const ushort8v*)&Ph[(size_t)r0 * 128 + cb];
        #pragma unroll
        for (int k = 0; k < 8; ++k)
            s0[k] += fmaxf(0.f, fmaf(h2f(v0[k]), av[k], bv[k]));
    }
    #pragma unroll
    for (int k = 0; k < 8; ++k) {
        float v = s0[k] + s1[k];
        v += __shfl_xor(v, 16);
        v += __shfl_xor(v, 32);
        s0[k] = v;
    }
    if (q == 0) {
        ushort8v o;
        #pragma unroll
        for (int k = 0; k < 8; ++k) o[k] = f2h(s0[k]);
        *(ushort8v*)&Gh[(size_t)wid * 128 + cb] = o;
    }
}

// ---------------------------------------------------------------------------
// GEMM body: 64-row tile, 256 threads (4 waves). B staged once per block into
// XOR-swizzled LDS (shared by 4 waves: 4x less L2 traffic, ~12cy ds_read in
// the MFMA loop instead of ~200cy L2 loads). A direct from global (transform
// in regs). f16 in/out, f32 accum, sliced stats epilogue.
// ---------------------------------------------------------------------------
template<int AMODE, bool RSC>
__device__ __forceinline__ void gemm_body(
    int row0, int t, int slice,
    const unsigned short* __restrict__ A, const unsigned short* __restrict__ A2,
    const unsigned short* __restrict__ Wt,
    const float* __restrict__ bias, const float* __restrict__ rowscale,
    const float* C1, const float* D1, const float* C2, const float* D2,
    const float* AE, const float* BE, const float* CE,
    const float* __restrict__ sN, const float* __restrict__ cN,
    unsigned short* __restrict__ Out, float* __restrict__ stats_out,
    unsigned short* Bs, float (*redS)[128], float (*redQ)[128])
{
    // ---- stage B (128x128 f16) into LDS with XOR swizzle (R5-proven)
    #pragma unroll
    for (int i = 0; i < 8; ++i) {
        int cch = t + i * 256;
        int n = cch >> 4, off = (cch & 15) << 3;
        ushort8v w = *(const ushort8v*)&Wt[n * 128 + off];
        *(ushort8v*)&Bs[(n * 128 + off) ^ ((n & 7) << 3)] = w;
    }

    const int w = t >> 6, lane = t & 63;
    const int la = lane & 15, lb = lane >> 4;
    const int ar = row0 + (w << 4) + la;
    const int kb = lb * 8;

    f16x8v afrag[4];
    #pragma unroll
    for (int s = 0; s < 4; ++s) {
        ushort8v avv = *(const ushort8v*)&A[(size_t)ar * 128 + s * 32 + kb];
        if (AMODE == 0) {
            afrag[s] = __builtin_bit_cast(f16x8v, avv);
        } else if (AMODE == 1) {
            f16x8v o;
            #pragma unroll
            for (int j = 0; j < 8; ++j) {
                int qq = s * 32 + kb + j;
                o[j] = (_Float16)fmaxf(0.f, fmaf(h2f(avv[j]), C1[qq], D1[qq]));
            }
            afrag[s] = o;
        } else {
            ushort8v gv = *(const ushort8v*)&A2[(size_t)ar * 128 + s * 32 + kb];
            float sr = sN[ar], cr = cN[ar];
            f16x8v o;
            #pragma unroll
            for (int j = 0; j < 8; ++j) {
                int qq = s * 32 + kb + j;
                float y = h2f(avv[j]) * C1[qq] + D1[qq] + h2f(gv[j]) * C2[qq] + D2[qq]
                        + sr * AE[qq] + cr * BE[qq] + CE[qq];
                o[j] = (_Float16)fmaxf(0.f, y);
            }
            afrag[s] = o;
        }
    }
    // one barrier: B staged (lgkm drained) AND all A/A2 reads of this 64-row
    // tile complete (vmcnt drained) before MFMA / in-place epilogue writes
    __syncthreads();

    f32x4v acc[8];
    #pragma unroll
    for (int c = 0; c < 8; ++c) acc[c] = (f32x4v){0.f, 0.f, 0.f, 0.f};

    #pragma unroll
    for (int c = 0; c < 8; ++c) {
        int bn_ = (c << 4) + la;
        int bbase = bn_ * 128;
        int bswz = (bn_ & 7) << 3;
        #pragma unroll
        for (int s = 0; s < 4; ++s) {
            f16x8v bf = *(const f16x8v*)&Bs[(bbase + s * 32 + kb) ^ bswz];
            acc[c] = __builtin_amdgcn_mfma_f32_16x16x32_f16(
                afrag[s], bf, acc[c], 0, 0, 0);
        }
    }

    const int orow0 = row0 + (w << 4) + lb * 4;
    float rsj[4];
    if (RSC) {
        #pragma unroll
        for (int j = 0; j < 4; ++j) rsj[j] = rowscale[orow0 + j];
    }
    float csum[8], csq[8];
    #pragma unroll
    for (int c = 0; c < 8; ++c) {
        int col = (c << 4) + la;
        float bc = bias[col];
        float s0 = 0.f, s1 = 0.f;
        #pragma unroll
        for (int j = 0; j < 4; ++j) {
            float v = acc[c][j] + (RSC ? rsj[j] * bc : bc);
            Out[(size_t)(orow0 + j) * 128 + col] = f2h(v);
            s0 += v; s1 += v * v;
        }
        csum[c] = s0; csq[c] = s1;
    }
    #pragma unroll
    for (int c = 0; c < 8; ++c) {
        csum[c] += __shfl_xor(csum[c], 16);
        csum[c] += __shfl_xor(csum[c], 32);
        csq[c]  += __shfl_xor(csq[c], 16);
        csq[c]  += __shfl_xor(csq[c], 32);
    }
    if (lane < 16) {
        #pragma unroll
        for (int c = 0; c < 8; ++c) {
            redS[w][(c << 4) + lane] = csum[c];
            redQ[w][(c << 4) + lane] = csq[c];
        }
    }
    __syncthreads();
    float* stS = stats_out + slice * 256;
    if (t < 128) {
        atomicAdd(&stS[t], redS[0][t] + redS[1][t] + redS[2][t] + redS[3][t]);
        atomicAdd(&stS[128 + t], redQ[0][t] + redQ[1][t] + redQ[2][t] + redQ[3][t]);
    }
}

// ---------------------------------------------------------------------------
// Dual GEMM: blocks [0,GB) node branch (AMODE1), [GB,2GB) neighbor (AMODE0+RSC)
// ---------------------------------------------------------------------------
__global__ __launch_bounds__(256) void dual_gemm_kernel(
    const unsigned short* __restrict__ Ph, unsigned short* __restrict__ Gh,
    const unsigned short* __restrict__ WtZ, const unsigned short* __restrict__ WtG,
    const float* __restrict__ bZ, const float* __restrict__ bG,
    const float* __restrict__ dg,
    const float* __restrict__ st1, const float* __restrict__ g1,
    const float* __restrict__ bt1,
    unsigned short* __restrict__ ZNh,
    float* __restrict__ statZN, float* __restrict__ statG)
{
    __shared__ __align__(16) unsigned short Bs[128 * 128];
    __shared__ float C1[128], D1[128];
    __shared__ float redS[4][128], redQ[4][128];
    const int t = threadIdx.x;
    const int b = blockIdx.x;

    if (b < GB) {
        bn_prep(st1, g1, bt1, C1, D1, t);
        __syncthreads();
        gemm_body<1, false>(b * 64, t, b & (NSLICE - 1),
            Ph, nullptr, WtZ, bZ, nullptr,
            C1, D1, nullptr, nullptr, nullptr, nullptr, nullptr,
            nullptr, nullptr, ZNh, statZN, Bs, redS, redQ);
    } else {
        gemm_body<0, true>((b - GB) * 64, t, b & (NSLICE - 1),
            Gh, nullptr, WtG, bG, dg,
            nullptr, nullptr, nullptr, nullptr, nullptr, nullptr, nullptr,
            nullptr, nullptr, Gh, statG, Bs, redS, redQ);
    }
}

// ---------------------------------------------------------------------------
// Standalone GEMM (64-row tiles). grid GB x 256 thr.
// ---------------------------------------------------------------------------
template<int AMODE, bool RSC>
__global__ __launch_bounds__(256) void mfma_gemm_kernel(
    const unsigned short* __restrict__ A, const unsigned short* __restrict__ A2,
    const unsigned short* __restrict__ Wt,
    const float* __restrict__ bias, const float* __restrict__ rowscale,
    const float* __restrict__ st1, const float* __restrict__ g1, const float* __restrict__ bt1,
    const float* __restrict__ st2, const float* __restrict__ g2, const float* __restrict__ bt2,
    const float* __restrict__ sN, const float* __restrict__ cN,
    const float* __restrict__ scal,
    const float* __restrict__ We, const float* __restrict__ Be,
    const float* __restrict__ ge, const float* __restrict__ bte,
    unsigned short* __restrict__ Out, float* __restrict__ stats_out)
{
    __shared__ __align__(16) unsigned short Bs[128 * 128];
    __shared__ float C1[128], D1[128], C2[128], D2[128];
    __shared__ float AE[128], BE[128], CE[128];
    __shared__ float redS[4][128], redQ[4][128];
    const int t = threadIdx.x;

    if (AMODE >= 1) {
        bn_prep(st1, g1, bt1, C1, D1, t);
    }
    if (AMODE == 2) {
        bn_prep(st2, g2, bt2, C2, D2, t);
        if (t < 128) {
            float ms = scal[0] * RCP_N, vs = scal[1] * RCP_N - ms * ms;
            float mc = scal[2] * RCP_N, vc = scal[3] * RCP_N - mc * mc;
            float cov = scal[4] * RCP_N - ms * mc;
            float we = We[t], be = Be[t];
            float me = ms * we + mc * be;
            float ve = we * we * vs + be * be * vc + 2.f * we * be * cov;
            float ae = ge[t] * rsqrtf(ve + BN_EPS);
            AE[t] = we * ae; BE[t] = be * ae; CE[t] = bte[t] - me * ae;
        }
    }
    if (AMODE >= 1) __syncthreads();

    gemm_body<AMODE, RSC>(blockIdx.x * 64, t, blockIdx.x & (NSLICE - 1),
        A, A2, Wt, bias, rowscale,
        C1, D1, C2, D2, AE, BE, CE,
        sN, cN, Out, stats_out, Bs, redS, redQ);
}

// Final elementwise: out(f32) = relu(bn(Z f16)), sliced stats input
__global__ __launch_bounds__(256) void bnrelu_kernel(
    const unsigned short* __restrict__ Z, const float* __restrict__ stz,
    const float* __restrict__ g, const float* __restrict__ bt,
    float* __restrict__ O)
{
    __shared__ float aT[128], bT[128];
    int t = threadIdx.x;
    bn_prep(stz, g, bt, aT, bT, t);
    __syncthreads();
    int stride = gridDim.x * 256;
    for (int idx = blockIdx.x * 256 + t; idx < N_NODES * 32; idx += stride) {
        int r = idx >> 5;
        int q = (idx & 31) * 4;
        ushort4 z = *(const ushort4*)&Z[(size_t)r * 128 + q];
        float4 o;
        o.x = fmaxf(0.f, fmaf(h2f(z.x), aT[q],     bT[q]));
        o.y = fmaxf(0.f, fmaf(h2f(z.y), aT[q + 1], bT[q + 1]));
        o.z = fmaxf(0.f, fmaf(h2f(z.z), aT[q + 2], bT[q + 2]));
        o.w = fmaxf(0.f, fmaf(h2f(z.w), aT[q + 3], bT[q + 3]));
        *(float4*)&O[(size_t)r * 128 + q] = o;
    }
}

// ---------------------------------------------------------------------------
extern "C" void kernel_launch(void* const* d_in, const int* in_sizes, int n_in,
                              void* d_out, int out_size, void* d_ws, size_t ws_size,
                              hipStream_t stream)
{
    const float* node_attr = (const float*)d_in[0];
    const int*   ei        = (const int*)d_in[1];
    const float* ea        = (const float*)d_in[2];
    const float* W0    = (const float*)d_in[3];
    const float* b0    = (const float*)d_in[4];
    const float* g0    = (const float*)d_in[5];
    const float* bt0   = (const float*)d_in[6];
    const float* Wnode = (const float*)d_in[7];
    const float* bnode = (const float*)d_in[8];
    const float* Wedge = (const float*)d_in[9];
    const float* bedge = (const float*)d_in[10];
    const float* Wnb   = (const float*)d_in[11];
    const float* bnb   = (const float*)d_in[12];
    const float* gn    = (const float*)d_in[13];
    const float* ge    = (const float*)d_in[14];
    const float* gnb   = (const float*)d_in[15];
    const float* gm1   = (const float*)d_in[16];
    const float* gm2   = (const float*)d_in[17];
    const float* btn   = (const float*)d_in[18];
    const float* bte   = (const float*)d_in[19];
    const float* btnb  = (const float*)d_in[20];
    const float* btm1  = (const float*)d_in[21];
    const float* btm2  = (const float*)d_in[22];
    const float* Wm1   = (const float*)d_in[23];
    const float* bm1   = (const float*)d_in[24];
    const float* Wm2   = (const float*)d_in[25];
    const float* bm2   = (const float*)d_in[26];
    float* out = (float*)d_out;

    // workspace: Ph|ZNh|Gh (f16, NF each) | sN|cN|dg (f32) | st(sliced stats)
    //            | scP(u64,N) | cursor(u32,N) | slot(int, N*CAP) | Wtb(f16)
    unsigned short* Ph  = (unsigned short*)d_ws;
    unsigned short* ZNh = Ph + NF;
    unsigned short* Gh  = ZNh + NF;
    float* sN = (float*)(Gh + NF);
    float* cN = sN + N_NODES;
    float* dg = cN + N_NODES;
    float* st = dg + N_NODES;
    // st layout: [0..4] moments | [256..256+STB) init stats |
    //            layer i stat j at 256+STB + (i*4+j)*STB  (j: zn,aggr,z1,z2)
    const size_t ST_FLOATS = 256 + (size_t)STB * 13;
    unsigned long long* scP = (unsigned long long*)(st + ST_FLOATS);
    unsigned* cursor = (unsigned*)(scP + N_NODES);
    int* slot = (int*)(cursor + N_NODES);
    unsigned short* Wtb = (unsigned short*)(slot + (size_t)N_NODES * CAP);
    float* stInit = st + 256;
    float* layBase = st + 256 + STB;

    // zero st | scP | cursor (contiguous)
    (void)hipMemsetAsync(st, 0, (ST_FLOATS + 3 * (size_t)N_NODES) * sizeof(float), stream);
    wprep_kernel<<<48, 256, 0, stream>>>(Wnode, Wnb, Wm1, Wm2, Wtb);
    edge_init_kernel<<<3125, 256, 0, stream>>>(
        node_attr, W0, b0, Ph, stInit, ei, ea, scP, cursor, slot);
    decode_kernel<<<157, 256, 0, stream>>>(scP, cursor, sN, cN, dg, st);

    const float* xst = stInit;
    const float* xg  = g0;
    const float* xbt = bt0;

    for (int i = 0; i < 3; ++i) {
        float* lay = layBase + (size_t)i * 4 * STB;
        // G = sum over in-neighbors of relu(bn(P[src]))
        gather_bn_kernel<<<10000, 256, 0, stream>>>(cursor, slot, Ph, xst, xg, xbt, Gh);
        // dual: ZN = relu(bn(P)) @ Wnode + bnode  ||  G = G @ Wnb + deg*bnb
        dual_gemm_kernel<<<2 * GB, 256, 0, stream>>>(
            Ph, Gh,
            Wtb + (size_t)(0 + i) * 16384, Wtb + (size_t)(3 + i) * 16384,
            bnode + i * 128, bnb + i * 128, dg,
            xst, xg, xbt,
            ZNh, lay, lay + STB);
        // z1 = relu(bn(ZN)+bn(G)+ea) @ Wm1 + bm1 (+stats) -> ZN (fused combine)
        mfma_gemm_kernel<2, false><<<GB, 256, 0, stream>>>(
            ZNh, Gh, Wtb + (size_t)(6 + i) * 16384, bm1 + i * 128, nullptr,
            lay, gn + i * 128, btn + i * 128,
            lay + STB, gnb + i * 128, btnb + i * 128,
            sN, cN, st,
            Wedge + i * 128, bedge + i * 128, ge + i * 128, bte + i * 128,
            ZNh, lay + 2 * STB);
        // z2 = relu(bn(z1)) @ Wm2 + bm2 (+stats) -> P
        mfma_gemm_kernel<1, false><<<GB, 256, 0, stream>>>(
            ZNh, nullptr, Wtb + (size_t)(9 + i) * 16384, bm2 + i * 128, nullptr,
            lay + 2 * STB, gm1 + i * 128, btm1 + i * 128, nullptr, nullptr, nullptr,
            nullptr, nullptr, nullptr, nullptr, nullptr, nullptr, nullptr,
            Ph, lay + 3 * STB);

        xst = lay + 3 * STB;
        xg  = gm2 + i * 128;
        xbt = btm2 + i * 128;
    }
    bnrelu_kernel<<<2048, 256, 0, stream>>>(Ph, xst, xg, xbt, out);
}